// Round 5
// baseline (144.850 us; speedup 1.0000x reference)
//
#include <hip/hip_runtime.h>
#include <hip/hip_fp16.h>

#define ODIM 128
#define INV_KEEP 1.1111112f   // float(1.0/0.9)

typedef float f4 __attribute__((ext_vector_type(4)));

// ---------- Fused prep kernel ----------
// Blocks [0, cvt_blocks): convert f32 W -> f16 into workspace (4 elems/thread).
// Blocks [cvt_blocks, ...): build CSR row_ptr from sorted rows[] by scatter.
__global__ void prep_kernel(const float* __restrict__ w, __half* __restrict__ wh,
                            int w_elems,
                            const int* __restrict__ rows, int* __restrict__ row_ptr,
                            int nnz, int n_nodes, int cvt_blocks) {
    if ((int)blockIdx.x < cvt_blocks) {
        int i4 = (blockIdx.x * 256 + threadIdx.x) * 4;
        if (i4 + 3 < w_elems) {
            float4 f = *(const float4*)(w + i4);
            *(__half2*)(wh + i4)     = __floats2half2_rn(f.x, f.y);
            *(__half2*)(wh + i4 + 2) = __floats2half2_rn(f.z, f.w);
        } else {
            for (int k = i4; k < w_elems; ++k) wh[k] = __float2half(w[k]);
        }
    } else {
        int i4 = ((blockIdx.x - cvt_blocks) * 256 + threadIdx.x) * 4;
        if (i4 >= nnz) return;
        int rprev = (i4 == 0) ? -1 : rows[i4 - 1];
        #pragma unroll
        for (int k = 0; k < 4; ++k) {
            int i = i4 + k;
            if (i < nnz) {
                int rc = rows[i];
                for (int r = rprev + 1; r <= rc; ++r) row_ptr[r] = i;
                if (i == nnz - 1)
                    for (int r = rc + 1; r <= n_nodes; ++r) row_ptr[r] = nnz;
                rprev = rc;
            }
        }
    }
}

// ---------- FMA helpers ----------
__device__ __forceinline__ void fma8h(float v, const uint4& h, float (&acc)[8]) {
    const __half2* hh = (const __half2*)&h;
    #pragma unroll
    for (int j = 0; j < 4; ++j) {    // fpext(f16)->fma fuses into v_fma_mix_f32
        acc[2*j]   = fmaf(v, __half2float(__low2half(hh[j])),  acc[2*j]);
        acc[2*j+1] = fmaf(v, __half2float(__high2half(hh[j])), acc[2*j+1]);
    }
}
__device__ __forceinline__ void fma8f(float v, const uint4& a, const uint4& b,
                                      float (&acc)[8]) {
    const float4 fa = *(const float4*)&a;
    const float4 fb = *(const float4*)&b;
    acc[0] = fmaf(v, fa.x, acc[0]);  acc[1] = fmaf(v, fa.y, acc[1]);
    acc[2] = fmaf(v, fa.z, acc[2]);  acc[3] = fmaf(v, fa.w, acc[3]);
    acc[4] = fmaf(v, fb.x, acc[4]);  acc[5] = fmaf(v, fb.y, acc[5]);
    acc[6] = fmaf(v, fb.z, acc[6]);  acc[7] = fmaf(v, fb.w, acc[7]);
}

// ---------- segment consume: quarter-wave gathers over slots [kb, ke) ----------
// No index clamps: the 80-slot LDS buffer has slots [64,80) zeroed once, so
// reads past the live region see v=0. PRED (segment A only) zeroes v for
// slots >= ke, because those slots hold segment B's LIVE values.
template <typename WT, bool PRED>
__device__ __forceinline__ void seg_gather(const char* __restrict__ wbase,
                                           const uint2* __restrict__ cvb,
                                           int kb, int ke, int q, unsigned lo,
                                           float (&acc)[8]) {
    for (int k0 = kb; k0 < ke; k0 += 16) {
        const int sl = k0 + q;                     // reads bounded by pad at 80
        const uint2 cv0 = cvb[sl];                 // ds_read_b64, bcast/quarter
        const uint2 cv1 = cvb[sl + 4];
        const uint2 cv2 = cvb[sl + 8];
        const uint2 cv3 = cvb[sl + 12];
        float v0 = __uint_as_float(cv0.y);
        float v1 = __uint_as_float(cv1.y);
        float v2 = __uint_as_float(cv2.y);
        float v3 = __uint_as_float(cv3.y);
        if constexpr (PRED) {
            v0 = (sl      < ke) ? v0 : 0.0f;
            v1 = (sl + 4  < ke) ? v1 : 0.0f;
            v2 = (sl + 8  < ke) ? v2 : 0.0f;
            v3 = (sl + 12 < ke) ? v3 : 0.0f;
        }
        if constexpr (sizeof(WT) == 2) {
            const uint4 h0 = *(const uint4*)(wbase + ((cv0.x << 8) | lo));
            const uint4 h1 = *(const uint4*)(wbase + ((cv1.x << 8) | lo));
            const uint4 h2 = *(const uint4*)(wbase + ((cv2.x << 8) | lo));
            const uint4 h3 = *(const uint4*)(wbase + ((cv3.x << 8) | lo));
            fma8h(v0, h0, acc);  fma8h(v1, h1, acc);
            fma8h(v2, h2, acc);  fma8h(v3, h3, acc);
        } else {
            const unsigned o0 = (cv0.x << 9) | lo;
            const unsigned o1 = (cv1.x << 9) | lo;
            const unsigned o2 = (cv2.x << 9) | lo;
            const unsigned o3 = (cv3.x << 9) | lo;
            const uint4 a0 = *(const uint4*)(wbase + o0);
            const uint4 b0 = *(const uint4*)(wbase + o0 + 16);
            const uint4 a1 = *(const uint4*)(wbase + o1);
            const uint4 b1 = *(const uint4*)(wbase + o1 + 16);
            const uint4 a2 = *(const uint4*)(wbase + o2);
            const uint4 b2 = *(const uint4*)(wbase + o2 + 16);
            const uint4 a3 = *(const uint4*)(wbase + o3);
            const uint4 b3 = *(const uint4*)(wbase + o3 + 16);
            fma8f(v0, a0, b0, acc);  fma8f(v1, a1, b1, acc);
            fma8f(v2, a2, b2, acc);  fma8f(v3, a3, b3, acc);
        }
    }
}

// ---------- Main SpMM: one wave per EIGHT consecutive rows (4 pairs) ----------
// Per-wave serial chain paid ONCE per 8 rows: one row_ptr wave-load gives all
// 9 boundaries; pair p+1's stream loads (cols/vals/mask) are issued BEFORE
// pair p's consume, hiding their latency under p's gathers.
template <typename WT>
__global__ void __launch_bounds__(256, 6)
spmm_kernel(const float* __restrict__ vals,
            const int*   __restrict__ rows,
            const int*   __restrict__ cols,
            const int*   __restrict__ mask,
            const WT*    __restrict__ wmat,
            const float* __restrict__ bias,
            const int*   __restrict__ row_ptr,   // may be null -> binary search
            float*       __restrict__ out,
            int nnz, int n_nodes) {
    __shared__ uint2 cvbuf[4][80];               // 64 live + 16 zero-pad per wave
    const int wave = threadIdx.x >> 6;
    const int lane = threadIdx.x & 63;
    const int q    = lane >> 4;                  // quarter 0..3
    const int s    = lane & 15;                  // sublane within quarter
    const int qh   = q & 1;
    const int r0   = (blockIdx.x * 4 + wave) * 8;
    if (r0 >= n_nodes) return;
    uint2* cvb = cvbuf[wave];
    if (lane < 16) cvb[64 + lane] = make_uint2(0u, 0u);   // pad, written once

    // ---- all 9 row boundaries with one wave-load ----
    int o0,o1,o2,o3,o4,o5,o6,o7,o8;
    {
        const int lk = lane < 9 ? lane : 8;
        int li = r0 + lk; li = li < n_nodes ? li : n_nodes;
        int t;
        if (row_ptr) {
            t = row_ptr[li];
        } else {
            int lo_ = 0, hi_ = nnz;
            while (lo_ < hi_) {
                int mid = (lo_ + hi_) >> 1;
                if (rows[mid] < li) lo_ = mid + 1; else hi_ = mid;
            }
            t = lo_;
        }
        o0 = __builtin_amdgcn_readlane(t, 0);
        o1 = __builtin_amdgcn_readlane(t, 1);
        o2 = __builtin_amdgcn_readlane(t, 2);
        o3 = __builtin_amdgcn_readlane(t, 3);
        o4 = __builtin_amdgcn_readlane(t, 4);
        o5 = __builtin_amdgcn_readlane(t, 5);
        o6 = __builtin_amdgcn_readlane(t, 6);
        o7 = __builtin_amdgcn_readlane(t, 7);
        o8 = __builtin_amdgcn_readlane(t, 8);
    }

    const char* wbase = (const char*)wmat;
    const unsigned lo16 = (sizeof(WT) == 2) ? ((unsigned)s << 4)
                                            : ((unsigned)s << 5);
    const int nnzm1 = nnz - 1;
    const int cb = 8 * s + 4 * qh;
    const float4 bvec = ((const float4*)bias)[(unsigned)cb >> 2];

    // ---- prologue: stream load for pair 0 ----
    int cN; float vN; int mN;
    {
        const int idx = o0 + lane;
        const int a = idx < nnzm1 ? idx : nnzm1;
        cN = __builtin_nontemporal_load(cols + a);
        vN = __builtin_nontemporal_load(vals + a);
        mN = __builtin_nontemporal_load(mask + a);
    }

#define DO_PAIR(BEG, MID, END, NBEG, LAST, RA)                                \
    {                                                                         \
        const int cC = cN; const float vC = vN; const int mC = mN;            \
        if (!(LAST)) {   /* issue next pair's streams; fly during consume */  \
            const int idxn = (NBEG) + lane;                                   \
            const int an = idxn < nnzm1 ? idxn : nnzm1;                       \
            cN = __builtin_nontemporal_load(cols + an);                       \
            vN = __builtin_nontemporal_load(vals + an);                       \
            mN = __builtin_nontemporal_load(mask + an);                       \
        }                                                                     \
        float aA[8] = {0.f,0.f,0.f,0.f,0.f,0.f,0.f,0.f};                      \
        float aB[8] = {0.f,0.f,0.f,0.f,0.f,0.f,0.f,0.f};                      \
        const int n_ = (END) - (BEG);                                         \
        {   /* stage chunk 0 (pads beyond END carry v=0) */                   \
            const int idx = (BEG) + lane;                                     \
            const float v_ = (idx < (END) && mC) ? vC * INV_KEEP : 0.0f;      \
            cvb[lane] = make_uint2((unsigned)cC, __float_as_uint(v_));        \
        }                                                                     \
        if (n_ <= 64) {                                                       \
            const int keA = (MID) - (BEG);                                    \
            seg_gather<WT, true >(wbase, cvb, 0,   keA, q, lo16, aA);         \
            seg_gather<WT, false>(wbase, cvb, keA, n_,  q, lo16, aB);         \
        } else {             /* rare: pair spans >64 nnz, chunked serial */   \
            int base = (BEG);                                                 \
            while (true) {                                                    \
                int keA = (MID) - base;                                       \
                keA = keA < 0 ? 0 : (keA > 64 ? 64 : keA);                    \
                int keB = (END) - base;                                       \
                keB = keB > 64 ? 64 : keB;                                    \
                seg_gather<WT, true >(wbase, cvb, 0,   keA, q, lo16, aA);     \
                seg_gather<WT, false>(wbase, cvb, keA, keB, q, lo16, aB);     \
                base += 64;                                                   \
                if (base >= (END)) break;                                     \
                const int idx = base + lane;                                  \
                const int a = idx < nnzm1 ? idx : nnzm1;                      \
                const int   c2 = __builtin_nontemporal_load(cols + a);        \
                const float v2 = __builtin_nontemporal_load(vals + a);        \
                const int   m2 = __builtin_nontemporal_load(mask + a);        \
                const float v_ = (idx < (END) && m2) ? v2 * INV_KEEP : 0.0f;  \
                cvb[lane] = make_uint2((unsigned)c2, __float_as_uint(v_));    \
            }                                                                 \
        }                                                                     \
        /* reduce quarters and store the pair's two rows */                   \
        _Pragma("unroll")                                                     \
        for (int j = 0; j < 8; ++j) {                                         \
            aA[j] += __shfl_xor(aA[j], 16);                                   \
            aB[j] += __shfl_xor(aB[j], 16);                                   \
        }                                                                     \
        float t0 = qh ? aA[4] : aA[0], u0 = qh ? aB[4] : aB[0];               \
        float t1 = qh ? aA[5] : aA[1], u1 = qh ? aB[5] : aB[1];               \
        float t2 = qh ? aA[6] : aA[2], u2 = qh ? aB[6] : aB[2];               \
        float t3 = qh ? aA[7] : aA[3], u3 = qh ? aB[7] : aB[3];               \
        t0 += __shfl_xor(t0, 32);  u0 += __shfl_xor(u0, 32);                  \
        t1 += __shfl_xor(t1, 32);  u1 += __shfl_xor(u1, 32);                  \
        t2 += __shfl_xor(t2, 32);  u2 += __shfl_xor(u2, 32);                  \
        t3 += __shfl_xor(t3, 32);  u3 += __shfl_xor(u3, 32);                  \
        if (q < 2) {                                                          \
            if ((RA) < n_nodes) {                                             \
                f4 o_;                                                        \
                o_.x = t0 + bvec.x;  o_.y = t1 + bvec.y;                      \
                o_.z = t2 + bvec.z;  o_.w = t3 + bvec.w;                      \
                __builtin_nontemporal_store(o_,                               \
                    (f4*)(out + (size_t)(RA) * ODIM + cb));                   \
            }                                                                 \
        } else {                                                              \
            if ((RA) + 1 < n_nodes) {                                         \
                f4 o_;                                                        \
                o_.x = u0 + bvec.x;  o_.y = u1 + bvec.y;                      \
                o_.z = u2 + bvec.z;  o_.w = u3 + bvec.w;                      \
                __builtin_nontemporal_store(o_,                               \
                    (f4*)(out + (size_t)((RA) + 1) * ODIM + cb));             \
            }                                                                 \
        }                                                                     \
    }

    DO_PAIR(o0, o1, o2, o2, 0, r0)
    DO_PAIR(o2, o3, o4, o4, 0, r0 + 2)
    DO_PAIR(o4, o5, o6, o6, 0, r0 + 4)
    DO_PAIR(o6, o7, o8, o8, 1, r0 + 6)
#undef DO_PAIR
}

extern "C" void kernel_launch(void* const* d_in, const int* in_sizes, int n_in,
                              void* d_out, int out_size, void* d_ws, size_t ws_size,
                              hipStream_t stream) {
    const float* vals = (const float*)d_in[0];
    const int*   rows = (const int*)  d_in[1];
    const int*   cols = (const int*)  d_in[2];
    const int*   mask = (const int*)  d_in[3];
    const float* W    = (const float*)d_in[4];
    const float* bias = (const float*)d_in[5];
    float*       out  = (float*)d_out;

    const int nnz     = in_sizes[0];
    const int w_elems = in_sizes[4];             // INPUT_DIM * OUTPUT_DIM
    const int n_nodes = out_size / ODIM;

    // workspace layout: [W as f16 (256B aligned) | row_ptr (n_nodes+1 ints)]
    const size_t wh_bytes = ((size_t)w_elems * sizeof(__half) + 255) & ~(size_t)255;
    const size_t rp_bytes = (size_t)(n_nodes + 1) * sizeof(int);

    __half* wh = nullptr;
    int* row_ptr = nullptr;
    if (ws_size >= wh_bytes + rp_bytes) {
        wh = (__half*)d_ws;
        row_ptr = (int*)((char*)d_ws + wh_bytes);
    } else if (ws_size >= rp_bytes) {
        row_ptr = (int*)d_ws;
    }

    const int cvt_blocks = wh ? (w_elems / 4 + 255) / 256 : 0;
    const int rp_blocks  = row_ptr ? ((nnz + 3) / 4 + 255) / 256 : 0;
    if (cvt_blocks + rp_blocks > 0)
        prep_kernel<<<cvt_blocks + rp_blocks, 256, 0, stream>>>(
            W, wh, w_elems, rows, row_ptr, nnz, n_nodes, cvt_blocks);

    const int blocks = (n_nodes + 31) / 32;  // 32 rows (4 waves x 8 rows) / block
    if (wh) {
        spmm_kernel<__half><<<blocks, 256, 0, stream>>>(
            vals, rows, cols, mask, wh, bias, row_ptr, out, nnz, n_nodes);
    } else {
        spmm_kernel<float><<<blocks, 256, 0, stream>>>(
            vals, rows, cols, mask, W, bias, row_ptr, out, nnz, n_nodes);
    }
}